// Round 3
// baseline (90.672 us; speedup 1.0000x reference)
//
#include <hip/hip_runtime.h>
#include <math.h>

#define M_DIM 1024
#define N_DIM 1024
#define NRANK 64
#define BN 16   // n-tile per block
#define BF 64   // f-tile per block

// Hf scratch in module-scope device memory (no d_ws assumptions).
__device__ float g_HfRe[NRANK * M_DIM];
__device__ float g_HfIm[NRANK * M_DIM];

__device__ __forceinline__ float softplus_f(float x) {
    return log1pf(__expf(x));
}

// ---------------------------------------------------------------------------
// Kernel 1: Hf[r, :] = FFT_1024( softplus(H[r, :]) )   (forward, e^{-2pi i fm/M})
// One block per rank row r; radix-2 DIT in LDS with bit-reversed load.
// ---------------------------------------------------------------------------
__global__ __launch_bounds__(512) void fft_rows(const float* __restrict__ H) {
    __shared__ float sre[M_DIM];
    __shared__ float sim[M_DIM];
    const int r = blockIdx.x;
    const int tid = threadIdx.x;

    for (int j = tid; j < M_DIM; j += 512) {
        int src = __brev((unsigned)j) >> 22;   // 10-bit reverse
        sre[j] = softplus_f(H[r * M_DIM + src]);
        sim[j] = 0.0f;
    }
    __syncthreads();

    int log2half = 0;
    for (int len = 2; len <= M_DIM; len <<= 1, ++log2half) {
        const int half = len >> 1;
        const int j    = tid & (half - 1);
        const int base = (tid >> log2half) << (log2half + 1);
        const int i0   = base + j;
        const int i1   = i0 + half;
        float s, c;
        __sincosf((-6.28318530717958647f / (float)len) * (float)j, &s, &c);
        const float xr = sre[i1], xi = sim[i1];
        const float vr = xr * c - xi * s;
        const float vi = xr * s + xi * c;
        const float ur = sre[i0], ui = sim[i0];
        sre[i0] = ur + vr;  sim[i0] = ui + vi;
        sre[i1] = ur - vr;  sim[i1] = ui - vi;
        __syncthreads();
    }

    for (int j = tid; j < M_DIM; j += 512) {
        g_HfRe[r * M_DIM + j] = sre[j];
        g_HfIm[r * M_DIM + j] = sim[j];
    }
}

// ---------------------------------------------------------------------------
// Kernel 2: WHt[n,f] = sum_r softplus(W[n,r]) * e^{-2pi i f tau[n,r]/M} * Hf[r,f]
// PLANAR output: out[n*M+f] = Re, out[N*M + n*M+f] = Im (harness flattens
// complex64 ref as real-plane then imag-plane — R2 forensics).
// ---------------------------------------------------------------------------
__global__ __launch_bounds__(256) void shiftnmf_main(
    const float* __restrict__ W, const float* __restrict__ tau,
    float* __restrict__ out, int out_elems) {

    __shared__ float shHr[NRANK][BF];   // 16 KB
    __shared__ float shHi[NRANK][BF];   // 16 KB
    __shared__ float shWp[BN][NRANK];   // 4 KB
    __shared__ float shA [BN][NRANK];   // 4 KB

    const int tid = threadIdx.x;
    const int f0  = blockIdx.x * BF;
    const int n0  = blockIdx.y * BN;

    for (int idx = tid; idx < NRANK * BF; idx += 256) {
        const int rr = idx >> 6, ff = idx & 63;
        shHr[rr][ff] = g_HfRe[rr * M_DIM + f0 + ff];
        shHi[rr][ff] = g_HfIm[rr * M_DIM + f0 + ff];
    }
    for (int idx = tid; idx < BN * NRANK; idx += 256) {
        const int nn = idx >> 6, rr = idx & 63;
        const int n  = n0 + nn;
        shWp[nn][rr] = softplus_f(W[n * NRANK + rr]);
        shA [nn][rr] = (-6.28318530717958647f / (float)M_DIM) * tau[n * NRANK + rr];
    }
    __syncthreads();

    const int ff  = tid & 63;
    const int ni0 = tid >> 6;                 // 0..3
    const float fglob = (float)(f0 + ff);

    float accRe[4] = {0.f, 0.f, 0.f, 0.f};
    float accIm[4] = {0.f, 0.f, 0.f, 0.f};

    for (int r = 0; r < NRANK; ++r) {
        const float hr = shHr[r][ff];         // stride-1 across wave: free
        const float hi = shHi[r][ff];
        #pragma unroll
        for (int k = 0; k < 4; ++k) {
            const int nn = ni0 + (k << 2);
            const float wp = shWp[nn][r];     // wave-uniform: broadcast
            const float a  = shA [nn][r];
            float s, c;
            __sincosf(a * fglob, &s, &c);     // angle in (-2pi, 0]
            const float wr = wp * hr;
            const float wi = wp * hi;
            accRe[k] = fmaf(c, wr, fmaf(-s, wi, accRe[k]));
            accIm[k] = fmaf(c, wi, fmaf( s, wr, accIm[k]));
        }
    }

    #pragma unroll
    for (int k = 0; k < 4; ++k) {
        const int n  = n0 + ni0 + (k << 2);
        const int oi = n * M_DIM + f0 + ff;
        if (oi < out_elems) out[oi] = accRe[k];                       // real plane
        const int oj = N_DIM * M_DIM + oi;
        if (oj < out_elems) out[oj] = accIm[k];                       // imag plane
    }
}

extern "C" void kernel_launch(void* const* d_in, const int* in_sizes, int n_in,
                              void* d_out, int out_size, void* d_ws, size_t ws_size,
                              hipStream_t stream) {
    const float* W   = (const float*)d_in[0];   // (1024, 64)
    const float* H   = (const float*)d_in[1];   // (64, 1024)
    const float* tau = (const float*)d_in[2];   // (1024, 64)

    (void)d_ws; (void)ws_size;

    fft_rows<<<NRANK, 512, 0, stream>>>(H);
    shiftnmf_main<<<dim3(M_DIM / BF, N_DIM / BN), 256, 0, stream>>>(
        W, tau, (float*)d_out, out_size);
}

// Round 4
// 88.328 us; speedup vs baseline: 1.0265x; 1.0265x over previous
//
#include <hip/hip_runtime.h>
#include <math.h>

#define M_DIM 1024
#define N_DIM 1024
#define NRANK 64
#define BN 16   // n-tile per block
#define BF 64   // f-tile per block

// Hf scratch in module-scope device memory (no d_ws assumptions).
__device__ float g_HfRe[NRANK * M_DIM];
__device__ float g_HfIm[NRANK * M_DIM];

__device__ __forceinline__ float softplus_f(float x) {
    return log1pf(__expf(x));
}

// Hardware transcendentals: v_sin_f32 / v_cos_f32 take input in REVOLUTIONS
// (D = sin(S0 * 2pi)). For |rev| < 1 no range reduction is needed.
// HIP's __sincosf lowers to the PRECISE __ocml_sincos_f32 (~40+ VALU instrs
// + Payne-Hanek) -- that was the R3 90us. These are 1 instr each.
__device__ __forceinline__ float fast_sin_rev(float rev) {
#if __has_builtin(__builtin_amdgcn_sinf)
    return __builtin_amdgcn_sinf(rev);
#else
    return __sinf(rev * 6.28318530717958647f);
#endif
}
__device__ __forceinline__ float fast_cos_rev(float rev) {
#if __has_builtin(__builtin_amdgcn_cosf)
    return __builtin_amdgcn_cosf(rev);
#else
    return __cosf(rev * 6.28318530717958647f);
#endif
}

// ---------------------------------------------------------------------------
// Kernel 1: Hf[r, :] = FFT_1024( softplus(H[r, :]) )   (forward, e^{-2pi i fm/M})
// One block per rank row r; radix-2 DIT in LDS with bit-reversed load.
// Twiddle angle as revolutions: rev = -j/len, exact in fp32 (pow2 divide).
// ---------------------------------------------------------------------------
__global__ __launch_bounds__(512) void fft_rows(const float* __restrict__ H) {
    __shared__ float sre[M_DIM];
    __shared__ float sim[M_DIM];
    const int r = blockIdx.x;
    const int tid = threadIdx.x;

    for (int j = tid; j < M_DIM; j += 512) {
        int src = __brev((unsigned)j) >> 22;   // 10-bit reverse
        sre[j] = softplus_f(H[r * M_DIM + src]);
        sim[j] = 0.0f;
    }
    __syncthreads();

    int log2half = 0;
    for (int len = 2; len <= M_DIM; len <<= 1, ++log2half) {
        const int half = len >> 1;
        const int j    = tid & (half - 1);
        const int base = (tid >> log2half) << (log2half + 1);
        const int i0   = base + j;
        const int i1   = i0 + half;
        const float rev = -(float)j / (float)len;   // in (-0.5, 0], exact
        const float s = fast_sin_rev(rev);
        const float c = fast_cos_rev(rev);
        const float xr = sre[i1], xi = sim[i1];
        const float vr = xr * c - xi * s;
        const float vi = xr * s + xi * c;
        const float ur = sre[i0], ui = sim[i0];
        sre[i0] = ur + vr;  sim[i0] = ui + vi;
        sre[i1] = ur - vr;  sim[i1] = ui - vi;
        __syncthreads();
    }

    for (int j = tid; j < M_DIM; j += 512) {
        g_HfRe[r * M_DIM + j] = sre[j];
        g_HfIm[r * M_DIM + j] = sim[j];
    }
}

// ---------------------------------------------------------------------------
// Kernel 2: WHt[n,f] = sum_r softplus(W[n,r]) * e^{-2pi i f tau[n,r]/M} * Hf[r,f]
// PLANAR output: out[n*M+f] = Re, out[N*M + n*M+f] = Im.
// Phase angle staged as REVOLUTIONS coefficient: arev = -tau/M, so
// rev = arev * f is in (-1, 0] -> single v_sin/v_cos, no range reduction.
// ---------------------------------------------------------------------------
__global__ __launch_bounds__(256) void shiftnmf_main(
    const float* __restrict__ W, const float* __restrict__ tau,
    float* __restrict__ out, int out_elems) {

    __shared__ float shHr[NRANK][BF];   // 16 KB
    __shared__ float shHi[NRANK][BF];   // 16 KB
    __shared__ float shWp[BN][NRANK];   // 4 KB
    __shared__ float shA [BN][NRANK];   // 4 KB (revolutions coefficient)

    const int tid = threadIdx.x;
    const int f0  = blockIdx.x * BF;
    const int n0  = blockIdx.y * BN;

    for (int idx = tid; idx < NRANK * BF; idx += 256) {
        const int rr = idx >> 6, ff = idx & 63;
        shHr[rr][ff] = g_HfRe[rr * M_DIM + f0 + ff];
        shHi[rr][ff] = g_HfIm[rr * M_DIM + f0 + ff];
    }
    for (int idx = tid; idx < BN * NRANK; idx += 256) {
        const int nn = idx >> 6, rr = idx & 63;
        const int n  = n0 + nn;
        shWp[nn][rr] = softplus_f(W[n * NRANK + rr]);
        shA [nn][rr] = (-1.0f / (float)M_DIM) * tau[n * NRANK + rr];
    }
    __syncthreads();

    const int ff  = tid & 63;
    const int ni0 = tid >> 6;                 // 0..3
    const float fglob = (float)(f0 + ff);

    float accRe[4] = {0.f, 0.f, 0.f, 0.f};
    float accIm[4] = {0.f, 0.f, 0.f, 0.f};

    for (int r = 0; r < NRANK; ++r) {
        const float hr = shHr[r][ff];         // stride-1 across wave: free
        const float hi = shHi[r][ff];
        #pragma unroll
        for (int k = 0; k < 4; ++k) {
            const int nn = ni0 + (k << 2);
            const float wp = shWp[nn][r];     // wave-uniform: broadcast
            const float a  = shA [nn][r];
            const float rev = a * fglob;      // in (-1, 0]
            const float s = fast_sin_rev(rev);
            const float c = fast_cos_rev(rev);
            const float wr = wp * hr;
            const float wi = wp * hi;
            accRe[k] = fmaf(c, wr, fmaf(-s, wi, accRe[k]));
            accIm[k] = fmaf(c, wi, fmaf( s, wr, accIm[k]));
        }
    }

    #pragma unroll
    for (int k = 0; k < 4; ++k) {
        const int n  = n0 + ni0 + (k << 2);
        const int oi = n * M_DIM + f0 + ff;
        if (oi < out_elems) out[oi] = accRe[k];                       // real plane
        const int oj = N_DIM * M_DIM + oi;
        if (oj < out_elems) out[oj] = accIm[k];                       // imag plane
    }
}

extern "C" void kernel_launch(void* const* d_in, const int* in_sizes, int n_in,
                              void* d_out, int out_size, void* d_ws, size_t ws_size,
                              hipStream_t stream) {
    const float* W   = (const float*)d_in[0];   // (1024, 64)
    const float* H   = (const float*)d_in[1];   // (64, 1024)
    const float* tau = (const float*)d_in[2];   // (1024, 64)

    (void)d_ws; (void)ws_size;

    fft_rows<<<NRANK, 512, 0, stream>>>(H);
    shiftnmf_main<<<dim3(M_DIM / BF, N_DIM / BN), 256, 0, stream>>>(
        W, tau, (float*)d_out, out_size);
}

// Round 5
// 86.850 us; speedup vs baseline: 1.0440x; 1.0170x over previous
//
#include <hip/hip_runtime.h>
#include <math.h>

#define M_DIM 1024
#define N_DIM 1024
#define NRANK 64
#define BN 16   // n-tile per block
#define BF 64   // f-tile per block

// Hf scratch in module-scope device memory (no d_ws assumptions).
__device__ float g_HfRe[NRANK * M_DIM];
__device__ float g_HfIm[NRANK * M_DIM];

__device__ __forceinline__ float softplus_f(float x) {
    return log1pf(__expf(x));
}

// v_sin_f32 / v_cos_f32: input in REVOLUTIONS (D = sin(S0*2pi)); |rev|<1 needs
// no range reduction. Single quarter-rate instruction each.
__device__ __forceinline__ float fast_sin_rev(float rev) {
#if __has_builtin(__builtin_amdgcn_sinf)
    return __builtin_amdgcn_sinf(rev);
#else
    return __sinf(rev * 6.28318530717958647f);
#endif
}
__device__ __forceinline__ float fast_cos_rev(float rev) {
#if __has_builtin(__builtin_amdgcn_cosf)
    return __builtin_amdgcn_cosf(rev);
#else
    return __cosf(rev * 6.28318530717958647f);
#endif
}

// ---------------------------------------------------------------------------
// Kernel 1: Hf[r, :] = FFT_1024( softplus(H[r, :]) )
// ---------------------------------------------------------------------------
__global__ __launch_bounds__(512) void fft_rows(const float* __restrict__ H) {
    __shared__ float sre[M_DIM];
    __shared__ float sim[M_DIM];
    const int r = blockIdx.x;
    const int tid = threadIdx.x;

    for (int j = tid; j < M_DIM; j += 512) {
        int src = __brev((unsigned)j) >> 22;   // 10-bit reverse
        sre[j] = softplus_f(H[r * M_DIM + src]);
        sim[j] = 0.0f;
    }
    __syncthreads();

    int log2half = 0;
    for (int len = 2; len <= M_DIM; len <<= 1, ++log2half) {
        const int half = len >> 1;
        const int j    = tid & (half - 1);
        const int base = (tid >> log2half) << (log2half + 1);
        const int i0   = base + j;
        const int i1   = i0 + half;
        const float rev = -(float)j / (float)len;   // (-0.5, 0], exact
        const float s = fast_sin_rev(rev);
        const float c = fast_cos_rev(rev);
        const float xr = sre[i1], xi = sim[i1];
        const float vr = xr * c - xi * s;
        const float vi = xr * s + xi * c;
        const float ur = sre[i0], ui = sim[i0];
        sre[i0] = ur + vr;  sim[i0] = ui + vi;
        sre[i1] = ur - vr;  sim[i1] = ui - vi;
        __syncthreads();
    }

    for (int j = tid; j < M_DIM; j += 512) {
        g_HfRe[r * M_DIM + j] = sre[j];
        g_HfIm[r * M_DIM + j] = sim[j];
    }
}

// ---------------------------------------------------------------------------
// Kernel 2: WHt[n,f] = sum_r softplus(W[n,r]) * e^{-2pi i f tau[n,r]/M} * Hf[r,f]
// PLANAR output (real plane then imag plane).
// Thread owns ONE n, FOUR f's (f = f0 + fbase + 16k). Phase at f advanced by
// precomputed per-(n,r) step e^{-2pi i a*16} -> trans ops per term: 2 -> 0.5.
// wp folded into initial phase so the accumulate is one 4-FMA complex mul-add.
// ---------------------------------------------------------------------------
__global__ __launch_bounds__(256) void shiftnmf_main(
    const float* __restrict__ W, const float* __restrict__ tau,
    float* __restrict__ out, int out_elems) {

    __shared__ float shHr[NRANK][BF];   // 16 KB
    __shared__ float shHi[NRANK][BF];   // 16 KB
    __shared__ float shWp[NRANK][BN];   // 4 KB  [r][n]: wave reads conflict-free
    __shared__ float shA [NRANK][BN];   // 4 KB  revolutions coeff a = -tau/M
    __shared__ float shSc[NRANK][BN];   // 4 KB  cos of step = e^{-2pi i a*16}
    __shared__ float shSs[NRANK][BN];   // 4 KB  sin of step

    const int tid = threadIdx.x;
    const int f0  = blockIdx.x * BF;
    const int n0  = blockIdx.y * BN;

    for (int idx = tid; idx < NRANK * BF; idx += 256) {
        const int rr = idx >> 6, ff = idx & 63;
        shHr[rr][ff] = g_HfRe[rr * M_DIM + f0 + ff];
        shHi[rr][ff] = g_HfIm[rr * M_DIM + f0 + ff];
    }
    for (int idx = tid; idx < BN * NRANK; idx += 256) {
        const int nn = idx >> 6, rr = idx & 63;   // rr fastest: coalesced W/tau reads
        const int n  = n0 + nn;
        const float wp = softplus_f(W[n * NRANK + rr]);
        const float a  = (-1.0f / (float)M_DIM) * tau[n * NRANK + rr];
        shWp[rr][nn] = wp;
        shA [rr][nn] = a;
        const float rev16 = a * 16.0f;            // |rev16| < 1/64
        shSc[rr][nn] = fast_cos_rev(rev16);
        shSs[rr][nn] = fast_sin_rev(rev16);
    }
    __syncthreads();

    const int fbase = tid & 15;                   // 0..15
    const int n_loc = tid >> 4;                   // 0..15
    const float fglob = (float)(f0 + fbase);

    float accRe[4] = {0.f, 0.f, 0.f, 0.f};
    float accIm[4] = {0.f, 0.f, 0.f, 0.f};

    for (int r = 0; r < NRANK; ++r) {
        const float wp  = shWp[r][n_loc];
        const float a   = shA [r][n_loc];
        const float c16 = shSc[r][n_loc];
        const float s16 = shSs[r][n_loc];
        const float rev0 = a * fglob;             // in (-1, 0]
        const float s0 = fast_sin_rev(rev0);
        const float c0 = fast_cos_rev(rev0);
        float pr = wp * c0;                       // wp folded into phase
        float pi = wp * s0;
        #pragma unroll
        for (int k = 0; k < 4; ++k) {
            const float hr = shHr[r][fbase + (k << 4)];  // 16 addrs x4 bcast: free
            const float hi = shHi[r][fbase + (k << 4)];
            accRe[k] = fmaf(pr, hr, fmaf(-pi, hi, accRe[k]));
            accIm[k] = fmaf(pr, hi, fmaf( pi, hr, accIm[k]));
            if (k < 3) {
                const float npr = fmaf(pr, c16, -pi * s16);  // phase *= step
                pi = fmaf(pr, s16, pi * c16);
                pr = npr;
            }
        }
    }

    #pragma unroll
    for (int k = 0; k < 4; ++k) {
        const int n  = n0 + n_loc;
        const int oi = n * M_DIM + f0 + fbase + (k << 4);
        if (oi < out_elems) out[oi] = accRe[k];                      // real plane
        const int oj = N_DIM * M_DIM + oi;
        if (oj < out_elems) out[oj] = accIm[k];                      // imag plane
    }
}

extern "C" void kernel_launch(void* const* d_in, const int* in_sizes, int n_in,
                              void* d_out, int out_size, void* d_ws, size_t ws_size,
                              hipStream_t stream) {
    const float* W   = (const float*)d_in[0];   // (1024, 64)
    const float* H   = (const float*)d_in[1];   // (64, 1024)
    const float* tau = (const float*)d_in[2];   // (1024, 64)

    (void)d_ws; (void)ws_size;

    fft_rows<<<NRANK, 512, 0, stream>>>(H);
    shiftnmf_main<<<dim3(M_DIM / BF, N_DIM / BN), 256, 0, stream>>>(
        W, tau, (float*)d_out, out_size);
}